// Round 10
// baseline (641.533 us; speedup 1.0000x reference)
//
#include <hip/hip_runtime.h>
#include <hip/hip_bf16.h>

#define GN 8192
#define KD 256
#define OD 64
#define LOG2E 1.44269504f
#define NCH 16        // 16 chunks x 256 j = 4096-j slice per block
#define WSTR 68       // wave-private LDS row stride (ints), 16B aligned
#define SLOT (16 * WSTR)        // 1088 ints per slot
#define WREG (2 * SLOT)         // 2176 ints per wave (dbuf)

typedef __attribute__((ext_vector_type(8))) short bf16x8;
typedef __attribute__((ext_vector_type(4))) float f32x4;

__device__ __forceinline__ float fexp2(float x) {
#if __has_builtin(__builtin_amdgcn_exp2f)
  return __builtin_amdgcn_exp2f(x);
#else
  return exp2f(x);
#endif
}

// ---------------------------------------------------------------------------
// Kernel 1: h = input @ W (fp32). Emits hTt (bf16, TILED [j/32][col][j%32] so
// k2's B-frag loads are contiguous 1KB bursts), f1p/f2p fp32 pre-scaled by
// log2(e), and the 3 scalar e-outputs.
// ---------------------------------------------------------------------------
__global__ __launch_bounds__(256) void gat_k1(
    const float* __restrict__ input, const float* __restrict__ W,
    const float* __restrict__ a, __hip_bfloat16* __restrict__ hTt,
    float* __restrict__ f1p, float* __restrict__ f2p, float* __restrict__ out)
{
  __shared__ float Wl[KD * OD];        // 64 KB, [k][c]
  __shared__ float inT[KD * 33];       // [k][r], pad 33
  __shared__ float red1[8][32];
  __shared__ float red2[8][32];
  __shared__ float s1row[32];
  __shared__ float s2row[32];

  const int tid = threadIdx.x;
  const int i0 = blockIdx.x * 32;

  for (int idx = tid; idx < KD * OD / 4; idx += 256)
    ((float4*)Wl)[idx] = ((const float4*)W)[idx];

#pragma unroll
  for (int it = 0; it < 8; ++it) {
    int idx = tid + it * 256;
    int r = idx >> 6, k4 = idx & 63;
    float4 v = *(const float4*)(input + (long)(i0 + r) * KD + k4 * 4);
    inT[(k4 * 4 + 0) * 33 + r] = v.x;
    inT[(k4 * 4 + 1) * 33 + r] = v.y;
    inT[(k4 * 4 + 2) * 33 + r] = v.z;
    inT[(k4 * 4 + 3) * 33 + r] = v.w;
  }
  __syncthreads();

  const int r = tid & 31;
  const int cg = tid >> 5;
  float acc[8];
#pragma unroll
  for (int c = 0; c < 8; ++c) acc[c] = 0.f;

#pragma unroll 4
  for (int k = 0; k < KD; ++k) {
    float inv = inT[k * 33 + r];
    float4 wa = *(const float4*)&Wl[k * 64 + cg * 8];
    float4 wb = *(const float4*)&Wl[k * 64 + cg * 8 + 4];
    acc[0] += inv * wa.x; acc[1] += inv * wa.y;
    acc[2] += inv * wa.z; acc[3] += inv * wa.w;
    acc[4] += inv * wb.x; acc[5] += inv * wb.y;
    acc[6] += inv * wb.z; acc[7] += inv * wb.w;
  }

#pragma unroll
  for (int c = 0; c < 8; ++c)
    hTt[(long)blockIdx.x * (OD * 32) + (cg * 8 + c) * 32 + r] =
        __float2bfloat16(acc[c]);

  float s1 = 0.f, s2 = 0.f;
#pragma unroll
  for (int c = 0; c < 8; ++c) {
    s1 += acc[c] * a[cg * 8 + c];
    s2 += acc[c] * a[OD + cg * 8 + c];
  }
  red1[cg][r] = s1; red2[cg][r] = s2;
  __syncthreads();
  if (tid < 32) {
    float f1 = 0.f, f2 = 0.f;
#pragma unroll
    for (int g = 0; g < 8; ++g) { f1 += red1[g][tid]; f2 += red2[g][tid]; }
    s1row[tid] = f1; s2row[tid] = f2;
    f1p[i0 + tid] = f1 * LOG2E;
    f2p[i0 + tid] = f2 * LOG2E;
  }
  __syncthreads();
  if (blockIdx.x == 0 && tid == 0) {
    float e12 = s1row[1] + s2row[2];
    float e13 = s1row[1] + s2row[3];
    float e32 = s1row[3] + s2row[2];
    out[(long)GN * OD + 0] = fmaxf(e12, 0.01f * e12);
    out[(long)GN * OD + 1] = fmaxf(e13, 0.01f * e13);
    out[(long)GN * OD + 2] = fmaxf(e32, 0.01f * e32);
  }
}

// ---------------------------------------------------------------------------
// Kernel 2: fused mask+softmax(no-max)+alpha@h over a 4096-j slice.
// BARRIER-FREE main loop with wave-private LDS staging:
//   each wave stages (global->VGPR->ds_write) exactly the 16 rows x 64 j it
//   consumes, so no __syncthreads (no vmcnt(0) drain) is ever needed.
// FIFO age discipline per iteration:
//   issue B(c+1)  ->  compute(c)        [waits drain <= B(c): 1 chunk old]
//   ds_write(c+1) [waits adj(c+1): 1 chunk old; B(c+1) younger, untouched]
//   issue adj(c+2) into st[]            [st regs free after the ds_write]
// ~12 KB in flight per wave x 12 waves/CU. f2 slice in LDS (staged once).
// 1024 blocks = 512 rowgroups x 2 j-slices; 3 blocks/CU (50 KB LDS).
// ---------------------------------------------------------------------------
__global__ __launch_bounds__(256, 3) void gat_k2(
    const int* __restrict__ adj, const __hip_bfloat16* __restrict__ hTt,
    const float* __restrict__ f1p, const float* __restrict__ f2p,
    float* __restrict__ pn, float* __restrict__ pd)
{
  __shared__ int abuf[4 * WREG];       // 34.8 KB wave-private adj dbuf
  __shared__ float f2l[4096];          // 16 KB f2 slice
  float* pb = (float*)abuf;            // epilogue overlay [4][16][68]
  float* sb = pb + 4 * 16 * 68;        // [4][16]

  const int tid = threadIdx.x;
  const int lane = tid & 63;
  const int wv = tid >> 6;             // wave -> j-quarter of each chunk
  const int tn = lane & 15;
  const int quad = lane >> 4;
  const int rg = blockIdx.x >> 1;
  const int js = blockIdx.x & 1;
  const int i0 = rg * 16;
  const int jbase = js * 4096;

  // stage f2 slice (16 KB) once
  for (int i = tid; i < 4096 / 4; i += 256)
    ((float4*)f2l)[i] = ((const float4*)(f2p + jbase))[i];

  const float f1r = f1p[i0 + tn];

  // wave-private staging addresses: lane -> row (lane>>2), 4 int4 segments
  const int sr = lane >> 2;            // 0..15
  const int sc = (lane & 3) * 4;       // 0,4,8,12
  const int* gsrc = adj + (long)(i0 + sr) * GN + jbase + wv * 64 + sc;
  const int wbase = wv * WREG;
  const int wrlds = wbase + sr * WSTR + sc;    // ds_write lane base (+16*k)

  // A-frag ds_read base: row tn, j-within-64 = ks*32 + quad*8
  const int ardbase = wbase + tn * WSTR + quad * 8;

  // B-frag base: slice index = jbase/32 + c*8 + wv*2 + ks
  const __hip_bfloat16* hsl =
      hTt + (long)(jbase / 32 + wv * 2) * (OD * 32) + tn * 32 + quad * 8;
  const float* f2q = f2l + wv * 64 + quad * 8;

  f32x4 acc[4];
#pragma unroll
  for (int nf = 0; nf < 4; ++nf) acc[nf] = (f32x4){0.f, 0.f, 0.f, 0.f};
  f32x4 accS = (f32x4){0.f, 0.f, 0.f, 0.f};

  bf16x8 ones;
  {
    short ov = (tn == 0) ? (short)0x3F80 : (short)0;
#pragma unroll
    for (int i = 0; i < 8; ++i) ones[i] = ov;
  }

  int4 st[4];
  bf16x8 B[2][8];   // [chunk parity][ks*4+nf]

  // ---- prologue ----
  // adj(0) -> slot 0
#pragma unroll
  for (int k = 0; k < 4; ++k) st[k] = *(const int4*)(gsrc + 16 * k);
#pragma unroll
  for (int k = 0; k < 4; ++k) *(int4*)&abuf[wrlds + 16 * k] = st[k];
  // adj(1) in flight
#pragma unroll
  for (int k = 0; k < 4; ++k) st[k] = *(const int4*)(gsrc + 256 + 16 * k);
  // B(0)
#pragma unroll
  for (int ks = 0; ks < 2; ++ks)
#pragma unroll
    for (int nf = 0; nf < 4; ++nf)
      B[0][ks * 4 + nf] =
          *(const bf16x8*)(hsl + (long)ks * (OD * 32) + nf * (16 * 32));

  for (int c = 0; c < NCH; ++c) {
    const int cur = c & 1, nxt = cur ^ 1;

    // issue B(c+1) (younger than adj(c+1); older than adj(c+2))
    if (c + 1 < NCH) {
      const __hip_bfloat16* hn = hsl + (long)((c + 1) * 8) * (OD * 32);
#pragma unroll
      for (int ks = 0; ks < 2; ++ks)
#pragma unroll
        for (int nf = 0; nf < 4; ++nf)
          B[nxt][ks * 4 + nf] =
              *(const bf16x8*)(hn + (long)ks * (OD * 32) + nf * (16 * 32));
    }

    // ---- compute chunk c (A from wave-private LDS slot, f2 from LDS) ----
#pragma unroll
    for (int ks = 0; ks < 2; ++ks) {
      const int4 a0 = *(const int4*)&abuf[ardbase + cur * SLOT + ks * 32];
      const int4 a1 = *(const int4*)&abuf[ardbase + cur * SLOT + ks * 32 + 4];
      const float4 f20 = *(const float4*)(f2q + c * 256 + ks * 32);
      const float4 f21 = *(const float4*)(f2q + c * 256 + ks * 32 + 4);

      float e0 = f1r + f20.x, e1 = f1r + f20.y, e2 = f1r + f20.z, e3 = f1r + f20.w;
      float e4 = f1r + f21.x, e5 = f1r + f21.y, e6 = f1r + f21.z, e7 = f1r + f21.w;
      float v0 = fexp2((a0.x > 0) ? fmaxf(e0, 0.01f * e0) : -256.f);
      float v1 = fexp2((a0.y > 0) ? fmaxf(e1, 0.01f * e1) : -256.f);
      float v2 = fexp2((a0.z > 0) ? fmaxf(e2, 0.01f * e2) : -256.f);
      float v3 = fexp2((a0.w > 0) ? fmaxf(e3, 0.01f * e3) : -256.f);
      float v4 = fexp2((a1.x > 0) ? fmaxf(e4, 0.01f * e4) : -256.f);
      float v5 = fexp2((a1.y > 0) ? fmaxf(e5, 0.01f * e5) : -256.f);
      float v6 = fexp2((a1.z > 0) ? fmaxf(e6, 0.01f * e6) : -256.f);
      float v7 = fexp2((a1.w > 0) ? fmaxf(e7, 0.01f * e7) : -256.f);

      union { bf16x8 v; unsigned u[4]; } wf;
      wf.u[0] = __builtin_amdgcn_perm(__float_as_uint(v1), __float_as_uint(v0), 0x07060302u);
      wf.u[1] = __builtin_amdgcn_perm(__float_as_uint(v3), __float_as_uint(v2), 0x07060302u);
      wf.u[2] = __builtin_amdgcn_perm(__float_as_uint(v5), __float_as_uint(v4), 0x07060302u);
      wf.u[3] = __builtin_amdgcn_perm(__float_as_uint(v7), __float_as_uint(v6), 0x07060302u);

#pragma unroll
      for (int nf = 0; nf < 4; ++nf)
        acc[nf] = __builtin_amdgcn_mfma_f32_16x16x32_bf16(
            wf.v, B[cur][ks * 4 + nf], acc[nf], 0, 0, 0);
      accS = __builtin_amdgcn_mfma_f32_16x16x32_bf16(wf.v, ones, accS, 0, 0, 0);
    }

    // commit adj(c+1) (waits only adj(c+1): 1 chunk old; B(c+1) untouched)
    if (c + 1 < NCH) {
#pragma unroll
      for (int k = 0; k < 4; ++k)
        *(int4*)&abuf[wrlds + nxt * SLOT + 16 * k] = st[k];
      // issue adj(c+2) into freed st regs (youngest in FIFO)
      if (c + 2 < NCH) {
#pragma unroll
        for (int k = 0; k < 4; ++k)
          st[k] = *(const int4*)(gsrc + (c + 2) * 256 + 16 * k);
      }
    }
  }

  // ---- epilogue: one barrier, overlay partials on abuf, write to gmem ----
  __syncthreads();
#pragma unroll
  for (int nf = 0; nf < 4; ++nf)
#pragma unroll
    for (int rgi = 0; rgi < 4; ++rgi)
      pb[(wv * 16 + quad * 4 + rgi) * 68 + nf * 16 + tn] = acc[nf][rgi];
  if (tn == 0) {
#pragma unroll
    for (int rgi = 0; rgi < 4; ++rgi)
      sb[wv * 16 + quad * 4 + rgi] = accS[rgi];
  }
  __syncthreads();
  for (int t = tid; t < 16 * OD; t += 256) {
    int rr = t >> 6, cc = t & 63;
    float num = pb[(0 * 16 + rr) * 68 + cc] + pb[(1 * 16 + rr) * 68 + cc] +
                pb[(2 * 16 + rr) * 68 + cc] + pb[(3 * 16 + rr) * 68 + cc];
    pn[((long)js * GN + i0 + rr) * OD + cc] = num;
  }
  if (tid < 16) {
    float den = sb[0 * 16 + tid] + sb[1 * 16 + tid] + sb[2 * 16 + tid] + sb[3 * 16 + tid];
    pd[(long)js * GN + i0 + tid] = den;
  }
}

// ---------------------------------------------------------------------------
// Kernel 3: combine the 2 j-slices: out = (pn0+pn1)/(pd0+pd1)
// ---------------------------------------------------------------------------
__global__ __launch_bounds__(256) void gat_k3(
    const float* __restrict__ pn, const float* __restrict__ pd,
    float* __restrict__ out)
{
  long t = (long)blockIdx.x * 256 + threadIdx.x;
  int i = (int)(t >> 6);
  float num = pn[t] + pn[(long)GN * OD + t];
  float den = pd[i] + pd[GN + i];
  out[t] = num / den;
}

extern "C" void kernel_launch(void* const* d_in, const int* in_sizes, int n_in,
                              void* d_out, int out_size, void* d_ws, size_t ws_size,
                              hipStream_t stream) {
  const float* input = (const float*)d_in[0];
  const int* adj     = (const int*)d_in[1];
  const float* W     = (const float*)d_in[2];
  const float* a     = (const float*)d_in[3];
  float* out = (float*)d_out;

  char* ws = (char*)d_ws;
  __hip_bfloat16* hTt = (__hip_bfloat16*)ws;              // 1 MB (tiled)
  float* f1p = (float*)(ws + (size_t)OD * GN * 2);        // 32 KB
  float* f2p = f1p + GN;                                  // 32 KB
  float* pn  = f2p + GN;                                  // 4 MB
  float* pd  = pn + (size_t)2 * GN * OD;                  // 64 KB

  gat_k1<<<256, 256, 0, stream>>>(input, W, a, hTt, f1p, f2p, out);
  gat_k2<<<1024, 256, 0, stream>>>(adj, hTt, f1p, f2p, pn, pd);
  gat_k3<<<GN * OD / 256, 256, 0, stream>>>(pn, pd, out);
}

// Round 11
// 406.938 us; speedup vs baseline: 1.5765x; 1.5765x over previous
//
#include <hip/hip_runtime.h>
#include <hip/hip_bf16.h>

#define GN 8192
#define KD 256
#define OD 64
#define LOG2E 1.44269504f

typedef __attribute__((ext_vector_type(8))) short bf16x8;
typedef __attribute__((ext_vector_type(4))) float f32x4;
typedef __attribute__((ext_vector_type(4))) int i32x4;

__device__ __forceinline__ float fexp2(float x) {
#if __has_builtin(__builtin_amdgcn_exp2f)
  return __builtin_amdgcn_exp2f(x);
#else
  return exp2f(x);
#endif
}

__device__ __forceinline__ i32x4 nt_load(const int* p) {
#if __has_builtin(__builtin_nontemporal_load)
  return __builtin_nontemporal_load((const i32x4*)p);
#else
  return *(const i32x4*)p;
#endif
}

// ---------------------------------------------------------------------------
// Kernel 1: h = input @ W (fp32). Emits hTt (bf16, TILED [j/32][col][j%32] so
// k2's B-frag loads are contiguous 1KB bursts), f1p/f2p fp32 pre-scaled by
// log2(e), and the 3 scalar e-outputs.
// ---------------------------------------------------------------------------
__global__ __launch_bounds__(256) void gat_k1(
    const float* __restrict__ input, const float* __restrict__ W,
    const float* __restrict__ a, __hip_bfloat16* __restrict__ hTt,
    float* __restrict__ f1p, float* __restrict__ f2p, float* __restrict__ out)
{
  __shared__ float Wl[KD * OD];        // 64 KB, [k][c]
  __shared__ float inT[KD * 33];       // [k][r], pad 33
  __shared__ float red1[8][32];
  __shared__ float red2[8][32];
  __shared__ float s1row[32];
  __shared__ float s2row[32];

  const int tid = threadIdx.x;
  const int i0 = blockIdx.x * 32;

  for (int idx = tid; idx < KD * OD / 4; idx += 256)
    ((float4*)Wl)[idx] = ((const float4*)W)[idx];

#pragma unroll
  for (int it = 0; it < 8; ++it) {
    int idx = tid + it * 256;
    int r = idx >> 6, k4 = idx & 63;
    float4 v = *(const float4*)(input + (long)(i0 + r) * KD + k4 * 4);
    inT[(k4 * 4 + 0) * 33 + r] = v.x;
    inT[(k4 * 4 + 1) * 33 + r] = v.y;
    inT[(k4 * 4 + 2) * 33 + r] = v.z;
    inT[(k4 * 4 + 3) * 33 + r] = v.w;
  }
  __syncthreads();

  const int r = tid & 31;
  const int cg = tid >> 5;
  float acc[8];
#pragma unroll
  for (int c = 0; c < 8; ++c) acc[c] = 0.f;

#pragma unroll 4
  for (int k = 0; k < KD; ++k) {
    float inv = inT[k * 33 + r];
    float4 wa = *(const float4*)&Wl[k * 64 + cg * 8];
    float4 wb = *(const float4*)&Wl[k * 64 + cg * 8 + 4];
    acc[0] += inv * wa.x; acc[1] += inv * wa.y;
    acc[2] += inv * wa.z; acc[3] += inv * wa.w;
    acc[4] += inv * wb.x; acc[5] += inv * wb.y;
    acc[6] += inv * wb.z; acc[7] += inv * wb.w;
  }

#pragma unroll
  for (int c = 0; c < 8; ++c)
    hTt[(long)blockIdx.x * (OD * 32) + (cg * 8 + c) * 32 + r] =
        __float2bfloat16(acc[c]);

  float s1 = 0.f, s2 = 0.f;
#pragma unroll
  for (int c = 0; c < 8; ++c) {
    s1 += acc[c] * a[cg * 8 + c];
    s2 += acc[c] * a[OD + cg * 8 + c];
  }
  red1[cg][r] = s1; red2[cg][r] = s2;
  __syncthreads();
  if (tid < 32) {
    float f1 = 0.f, f2 = 0.f;
#pragma unroll
    for (int g = 0; g < 8; ++g) { f1 += red1[g][tid]; f2 += red2[g][tid]; }
    s1row[tid] = f1; s2row[tid] = f2;
    f1p[i0 + tid] = f1 * LOG2E;
    f2p[i0 + tid] = f2 * LOG2E;
  }
  __syncthreads();
  if (blockIdx.x == 0 && tid == 0) {
    float e12 = s1row[1] + s2row[2];
    float e13 = s1row[1] + s2row[3];
    float e32 = s1row[3] + s2row[2];
    out[(long)GN * OD + 0] = fmaxf(e12, 0.01f * e12);
    out[(long)GN * OD + 1] = fmaxf(e13, 0.01f * e13);
    out[(long)GN * OD + 2] = fmaxf(e32, 0.01f * e32);
  }
}

// ---------------------------------------------------------------------------
// Kernel 2: fused mask+softmax(no-max)+alpha@h over a 512-j wave slice.
// FULLY-UNROLLED 16-step loop, 3-deep register rotation with COMPILE-TIME
// indices (s%3 under full unroll) -> guaranteed VGPR residency (r10 failed
// on runtime-indexed register arrays -> scratch). adj loaded directly in
// A-frag layout via NON-TEMPORAL loads (stream-once; keeps hTt hot in L2).
// No barriers in the main loop. 2048 blocks = 512 rowgroups x 4 j-slices;
// block = 16 rows x 2048 j, wave = 16 rows x 512 j. LDS: f2 slice + epilogue.
// ---------------------------------------------------------------------------
__global__ __launch_bounds__(256, 3) void gat_k2(
    const int* __restrict__ adj, const __hip_bfloat16* __restrict__ hTt,
    const float* __restrict__ f1p, const float* __restrict__ f2p,
    float* __restrict__ pn, float* __restrict__ pd)
{
  __shared__ float f2l[2048];          // 8 KB
  __shared__ float pb[4][16][68];      // 17.4 KB
  __shared__ float sb[4][16];

  const int tid = threadIdx.x;
  const int lane = tid & 63;
  const int wv = tid >> 6;             // wave -> 512-j quarter of block slice
  const int tn = lane & 15;            // MFMA m/n index
  const int quad = lane >> 4;          // MFMA k-quad
  const int rg = blockIdx.x >> 2;
  const int js = blockIdx.x & 3;
  const int i0 = rg * 16;
  const int jbase = js * 2048;
  const int jw = jbase + wv * 512;

  // stage this block's f2 slice (8 KB)
  for (int i = tid; i < 2048 / 4; i += 256)
    ((float4*)f2l)[i] = ((const float4*)(f2p + jbase))[i];

  const float f1r = f1p[i0 + tn];
  __syncthreads();

  const int* ap = adj + (long)(i0 + tn) * GN + jw + quad * 8;
  const __hip_bfloat16* hsl =
      hTt + (long)(jw / 32) * (OD * 32) + tn * 32 + quad * 8;
  const float* f2q = f2l + wv * 512 + quad * 8;

  f32x4 acc[4];
#pragma unroll
  for (int nf = 0; nf < 4; ++nf) acc[nf] = (f32x4){0.f, 0.f, 0.f, 0.f};
  f32x4 accS = (f32x4){0.f, 0.f, 0.f, 0.f};

  bf16x8 ones;  // ones in column n==0 -> row sums via MFMA
  {
    short ov = (tn == 0) ? (short)0x3F80 : (short)0;
#pragma unroll
    for (int i = 0; i < 8; ++i) ones[i] = ov;
  }

  i32x4 A[3][2];
  bf16x8 B[3][4];

  // prologue: slices 0,1,2 in flight
#pragma unroll
  for (int s = 0; s < 3; ++s) {
    A[s][0] = nt_load(ap + s * 32);
    A[s][1] = nt_load(ap + s * 32 + 4);
#pragma unroll
    for (int nf = 0; nf < 4; ++nf)
      B[s][nf] = *(const bf16x8*)(hsl + (long)s * (OD * 32) + nf * (16 * 32));
  }

#pragma unroll
  for (int s = 0; s < 16; ++s) {
    const int sl = s % 3;               // compile-time under full unroll
    const i32x4 a0 = A[sl][0];
    const i32x4 a1 = A[sl][1];
    const bf16x8 b0 = B[sl][0], b1 = B[sl][1], b2 = B[sl][2], b3 = B[sl][3];

    if (s + 3 < 16) {  // refill slot sl with slice s+3 (renamed regs; issues early)
      A[sl][0] = nt_load(ap + (s + 3) * 32);
      A[sl][1] = nt_load(ap + (s + 3) * 32 + 4);
#pragma unroll
      for (int nf = 0; nf < 4; ++nf)
        B[sl][nf] =
            *(const bf16x8*)(hsl + (long)(s + 3) * (OD * 32) + nf * (16 * 32));
    }

    const float4 f20 = *(const float4*)(f2q + s * 32);
    const float4 f21 = *(const float4*)(f2q + s * 32 + 4);

    float e0 = f1r + f20.x, e1 = f1r + f20.y, e2 = f1r + f20.z, e3 = f1r + f20.w;
    float e4 = f1r + f21.x, e5 = f1r + f21.y, e6 = f1r + f21.z, e7 = f1r + f21.w;
    float v0 = fexp2((a0.x > 0) ? fmaxf(e0, 0.01f * e0) : -256.f);
    float v1 = fexp2((a0.y > 0) ? fmaxf(e1, 0.01f * e1) : -256.f);
    float v2 = fexp2((a0.z > 0) ? fmaxf(e2, 0.01f * e2) : -256.f);
    float v3 = fexp2((a0.w > 0) ? fmaxf(e3, 0.01f * e3) : -256.f);
    float v4 = fexp2((a1.x > 0) ? fmaxf(e4, 0.01f * e4) : -256.f);
    float v5 = fexp2((a1.y > 0) ? fmaxf(e5, 0.01f * e5) : -256.f);
    float v6 = fexp2((a1.z > 0) ? fmaxf(e6, 0.01f * e6) : -256.f);
    float v7 = fexp2((a1.w > 0) ? fmaxf(e7, 0.01f * e7) : -256.f);

    union { bf16x8 v; unsigned u[4]; } wf;
    wf.u[0] = __builtin_amdgcn_perm(__float_as_uint(v1), __float_as_uint(v0), 0x07060302u);
    wf.u[1] = __builtin_amdgcn_perm(__float_as_uint(v3), __float_as_uint(v2), 0x07060302u);
    wf.u[2] = __builtin_amdgcn_perm(__float_as_uint(v5), __float_as_uint(v4), 0x07060302u);
    wf.u[3] = __builtin_amdgcn_perm(__float_as_uint(v7), __float_as_uint(v6), 0x07060302u);

    acc[0] = __builtin_amdgcn_mfma_f32_16x16x32_bf16(wf.v, b0, acc[0], 0, 0, 0);
    acc[1] = __builtin_amdgcn_mfma_f32_16x16x32_bf16(wf.v, b1, acc[1], 0, 0, 0);
    acc[2] = __builtin_amdgcn_mfma_f32_16x16x32_bf16(wf.v, b2, acc[2], 0, 0, 0);
    acc[3] = __builtin_amdgcn_mfma_f32_16x16x32_bf16(wf.v, b3, acc[3], 0, 0, 0);
    accS   = __builtin_amdgcn_mfma_f32_16x16x32_bf16(wf.v, ones, accS, 0, 0, 0);
  }

  // epilogue: reduce the block's 4 wave j-partials, write slice partials
#pragma unroll
  for (int nf = 0; nf < 4; ++nf)
#pragma unroll
    for (int rgi = 0; rgi < 4; ++rgi)
      pb[wv][quad * 4 + rgi][nf * 16 + tn] = acc[nf][rgi];
  if (tn == 0) {
#pragma unroll
    for (int rgi = 0; rgi < 4; ++rgi)
      sb[wv][quad * 4 + rgi] = accS[rgi];
  }
  __syncthreads();
  for (int t = tid; t < 16 * OD; t += 256) {
    int rr = t >> 6, cc = t & 63;
    float num = pb[0][rr][cc] + pb[1][rr][cc] + pb[2][rr][cc] + pb[3][rr][cc];
    pn[((long)js * GN + i0 + rr) * OD + cc] = num;
  }
  if (tid < 16) {
    float den = sb[0][tid] + sb[1][tid] + sb[2][tid] + sb[3][tid];
    pd[(long)js * GN + i0 + tid] = den;
  }
}

// ---------------------------------------------------------------------------
// Kernel 3: combine the 4 j-slices: out = sum(pn)/sum(pd)
// ---------------------------------------------------------------------------
__global__ __launch_bounds__(256) void gat_k3(
    const float* __restrict__ pn, const float* __restrict__ pd,
    float* __restrict__ out)
{
  const long NO = (long)GN * OD;
  long t = (long)blockIdx.x * 256 + threadIdx.x;
  int i = (int)(t >> 6);
  float num = pn[t] + pn[NO + t] + pn[2 * NO + t] + pn[3 * NO + t];
  float den = pd[i] + pd[GN + i] + pd[2 * GN + i] + pd[3 * GN + i];
  out[t] = num / den;
}

extern "C" void kernel_launch(void* const* d_in, const int* in_sizes, int n_in,
                              void* d_out, int out_size, void* d_ws, size_t ws_size,
                              hipStream_t stream) {
  const float* input = (const float*)d_in[0];
  const int* adj     = (const int*)d_in[1];
  const float* W     = (const float*)d_in[2];
  const float* a     = (const float*)d_in[3];
  float* out = (float*)d_out;

  char* ws = (char*)d_ws;
  __hip_bfloat16* hTt = (__hip_bfloat16*)ws;              // 1 MB (tiled)
  float* f1p = (float*)(ws + (size_t)OD * GN * 2);        // 32 KB
  float* f2p = f1p + GN;                                  // 32 KB
  float* pn  = f2p + GN;                                  // 4 slices * 2 MB = 8 MB
  float* pd  = pn + (size_t)4 * GN * OD;                  // 128 KB

  gat_k1<<<256, 256, 0, stream>>>(input, W, a, hTt, f1p, f2p, out);
  gat_k2<<<2048, 256, 0, stream>>>(adj, hTt, f1p, f2p, pn, pd);
  gat_k3<<<GN * OD / 256, 256, 0, stream>>>(pn, pd, out);
}

// Round 12
// 391.079 us; speedup vs baseline: 1.6404x; 1.0406x over previous
//
#include <hip/hip_runtime.h>
#include <hip/hip_bf16.h>

#define GN 8192
#define KD 256
#define OD 64
#define LOG2E 1.44269504f
#define STR 532      // adj LDS row stride (ints): 2128 B, 16B-aligned
#define NSTRIP 16    // 16 strips x 512 j

typedef __attribute__((ext_vector_type(8))) short bf16x8;
typedef __attribute__((ext_vector_type(4))) float f32x4;

__device__ __forceinline__ float fexp2(float x) {
#if __has_builtin(__builtin_amdgcn_exp2f)
  return __builtin_amdgcn_exp2f(x);
#else
  return exp2f(x);
#endif
}

// async global->LDS, 16B/lane: lane i lands at ldsbase + i*16 (r5-validated).
__device__ __forceinline__ void async_cp16(const void* g, void* l) {
  __builtin_amdgcn_global_load_lds(
      (const __attribute__((address_space(1))) unsigned int*)g,
      (__attribute__((address_space(3))) unsigned int*)l, 16, 0, 0);
}

// ---------------------------------------------------------------------------
// Kernel 1: h = input @ W (fp32). Emits hTt (bf16, TILED [j/32][col][j%32]),
// f1p/f2p fp32 pre-scaled by log2(e), and the 3 scalar e-outputs.
// ---------------------------------------------------------------------------
__global__ __launch_bounds__(256) void gat_k1(
    const float* __restrict__ input, const float* __restrict__ W,
    const float* __restrict__ a, __hip_bfloat16* __restrict__ hTt,
    float* __restrict__ f1p, float* __restrict__ f2p, float* __restrict__ out)
{
  __shared__ float Wl[KD * OD];
  __shared__ float inT[KD * 33];
  __shared__ float red1[8][32];
  __shared__ float red2[8][32];
  __shared__ float s1row[32];
  __shared__ float s2row[32];

  const int tid = threadIdx.x;
  const int i0 = blockIdx.x * 32;

  for (int idx = tid; idx < KD * OD / 4; idx += 256)
    ((float4*)Wl)[idx] = ((const float4*)W)[idx];

#pragma unroll
  for (int it = 0; it < 8; ++it) {
    int idx = tid + it * 256;
    int r = idx >> 6, k4 = idx & 63;
    float4 v = *(const float4*)(input + (long)(i0 + r) * KD + k4 * 4);
    inT[(k4 * 4 + 0) * 33 + r] = v.x;
    inT[(k4 * 4 + 1) * 33 + r] = v.y;
    inT[(k4 * 4 + 2) * 33 + r] = v.z;
    inT[(k4 * 4 + 3) * 33 + r] = v.w;
  }
  __syncthreads();

  const int r = tid & 31;
  const int cg = tid >> 5;
  float acc[8];
#pragma unroll
  for (int c = 0; c < 8; ++c) acc[c] = 0.f;

#pragma unroll 4
  for (int k = 0; k < KD; ++k) {
    float inv = inT[k * 33 + r];
    float4 wa = *(const float4*)&Wl[k * 64 + cg * 8];
    float4 wb = *(const float4*)&Wl[k * 64 + cg * 8 + 4];
    acc[0] += inv * wa.x; acc[1] += inv * wa.y;
    acc[2] += inv * wa.z; acc[3] += inv * wa.w;
    acc[4] += inv * wb.x; acc[5] += inv * wb.y;
    acc[6] += inv * wb.z; acc[7] += inv * wb.w;
  }

#pragma unroll
  for (int c = 0; c < 8; ++c)
    hTt[(long)blockIdx.x * (OD * 32) + (cg * 8 + c) * 32 + r] =
        __float2bfloat16(acc[c]);

  float s1 = 0.f, s2 = 0.f;
#pragma unroll
  for (int c = 0; c < 8; ++c) {
    s1 += acc[c] * a[cg * 8 + c];
    s2 += acc[c] * a[OD + cg * 8 + c];
  }
  red1[cg][r] = s1; red2[cg][r] = s2;
  __syncthreads();
  if (tid < 32) {
    float f1 = 0.f, f2 = 0.f;
#pragma unroll
    for (int g = 0; g < 8; ++g) { f1 += red1[g][tid]; f2 += red2[g][tid]; }
    s1row[tid] = f1; s2row[tid] = f2;
    f1p[i0 + tid] = f1 * LOG2E;
    f2p[i0 + tid] = f2 * LOG2E;
  }
  __syncthreads();
  if (blockIdx.x == 0 && tid == 0) {
    float e12 = s1row[1] + s2row[2];
    float e13 = s1row[1] + s2row[3];
    float e32 = s1row[3] + s2row[2];
    out[(long)GN * OD + 0] = fmaxf(e12, 0.01f * e12);
    out[(long)GN * OD + 1] = fmaxf(e13, 0.01f * e13);
    out[(long)GN * OD + 2] = fmaxf(e32, 0.01f * e32);
  }
}

// ---------------------------------------------------------------------------
// Kernel 2: fused mask+softmax(no-max)+alpha@h.
// 256 blocks x 512 threads, 1 block/CU. Block = 32 rows x 8192 j, processed
// as 16 strips of 512 j. adj staged by fire-and-forget global_load_lds DMA
// bursts (8 x 1KB per wave per strip) into a 2x66.5KB LDS dbuf; one barrier
// per strip (drain amortized over ~6400-cyc strips). B-frags (tiled hTt) and
// f2 ride a 2-deep register rotation whose issues are ordered OLDER than the
// DMA burst -> no wait ever drains the DMAs early. Waves = 2 rowhalves x
// 4 j-subranges. Epilogue reduces in LDS (overlay), writes out directly.
// ---------------------------------------------------------------------------
struct BF { bf16x8 b0, b1, b2, b3; float4 fa, fb; };

__global__ __launch_bounds__(512, 2) void gat_k2(
    const int* __restrict__ adj, const __hip_bfloat16* __restrict__ hTt,
    const float* __restrict__ f1p, const float* __restrict__ f2p,
    float* __restrict__ out)
{
  __shared__ int abuf[2][32 * STR];   // 136 KB

  const int tid = threadIdx.x;
  const int lane = tid & 63;
  const int wv = tid >> 6;            // 0..7
  const int rh = wv >> 2;             // rowhalf
  const int jq = wv & 3;              // 128-j subrange within strip
  const int tn = lane & 15;
  const int quad = lane >> 4;
  const int i0 = blockIdx.x * 32;

  const float f1r = f1p[i0 + rh * 16 + tn];

  // DMA: wave stages rows wv*4..wv*4+3; src 1KB contiguous per instruction
  const int* dsrc = adj + (long)(i0 + wv * 4) * GN + lane * 4;

  // A-frag ds_read base (row rh*16+tn, j = jq*128 + sl*32 + quad*8)
  const int ard = (rh * 16 + tn) * STR + jq * 128 + quad * 8;

  // B-frag base: global slice index gs = t*16 + jq*4 + sl
  const __hip_bfloat16* hb = hTt + (long)(jq * 4) * (OD * 32) + tn * 32 + quad * 8;
  const float* f2g = f2p + jq * 128 + quad * 8;   // + t*512 + sl*32

  f32x4 acc[4];
#pragma unroll
  for (int nf = 0; nf < 4; ++nf) acc[nf] = (f32x4){0.f, 0.f, 0.f, 0.f};
  f32x4 accS = (f32x4){0.f, 0.f, 0.f, 0.f};

  bf16x8 ones;  // ones in column n==0 -> row sums via MFMA
  {
    short ov = (tn == 0) ? (short)0x3F80 : (short)0;
#pragma unroll
    for (int i = 0; i < 8; ++i) ones[i] = ov;
  }

  auto dma = [&](int strip, int buf) {
    const int js = strip * 512;
#pragma unroll
    for (int d = 0; d < 8; ++d) {
      const int r = d >> 1, hf = d & 1;
      async_cp16(dsrc + (long)r * GN + js + hf * 256,
                 &abuf[buf][(wv * 4 + r) * STR + hf * 256]);
    }
  };
  auto issueBF = [&](BF& dst, int t, int sl) {
    const __hip_bfloat16* p = hb + (long)(t * 16 + sl) * (OD * 32);
    dst.b0 = *(const bf16x8*)(p + 0 * (16 * 32));
    dst.b1 = *(const bf16x8*)(p + 1 * (16 * 32));
    dst.b2 = *(const bf16x8*)(p + 2 * (16 * 32));
    dst.b3 = *(const bf16x8*)(p + 3 * (16 * 32));
    dst.fa = *(const float4*)(f2g + t * 512 + sl * 32);
    dst.fb = *(const float4*)(f2g + t * 512 + sl * 32 + 4);
  };
  auto computeSlice = [&](const BF& cb, const int* ab, int sl) {
    const int4 a0 = *(const int4*)&ab[ard + sl * 32];
    const int4 a1 = *(const int4*)&ab[ard + sl * 32 + 4];
    float e0 = f1r + cb.fa.x, e1 = f1r + cb.fa.y, e2 = f1r + cb.fa.z, e3 = f1r + cb.fa.w;
    float e4 = f1r + cb.fb.x, e5 = f1r + cb.fb.y, e6 = f1r + cb.fb.z, e7 = f1r + cb.fb.w;
    float v0 = fexp2((a0.x > 0) ? fmaxf(e0, 0.01f * e0) : -256.f);
    float v1 = fexp2((a0.y > 0) ? fmaxf(e1, 0.01f * e1) : -256.f);
    float v2 = fexp2((a0.z > 0) ? fmaxf(e2, 0.01f * e2) : -256.f);
    float v3 = fexp2((a0.w > 0) ? fmaxf(e3, 0.01f * e3) : -256.f);
    float v4 = fexp2((a1.x > 0) ? fmaxf(e4, 0.01f * e4) : -256.f);
    float v5 = fexp2((a1.y > 0) ? fmaxf(e5, 0.01f * e5) : -256.f);
    float v6 = fexp2((a1.z > 0) ? fmaxf(e6, 0.01f * e6) : -256.f);
    float v7 = fexp2((a1.w > 0) ? fmaxf(e7, 0.01f * e7) : -256.f);
    union { bf16x8 v; unsigned u[4]; } wf;
    wf.u[0] = __builtin_amdgcn_perm(__float_as_uint(v1), __float_as_uint(v0), 0x07060302u);
    wf.u[1] = __builtin_amdgcn_perm(__float_as_uint(v3), __float_as_uint(v2), 0x07060302u);
    wf.u[2] = __builtin_amdgcn_perm(__float_as_uint(v5), __float_as_uint(v4), 0x07060302u);
    wf.u[3] = __builtin_amdgcn_perm(__float_as_uint(v7), __float_as_uint(v6), 0x07060302u);
    acc[0] = __builtin_amdgcn_mfma_f32_16x16x32_bf16(wf.v, cb.b0, acc[0], 0, 0, 0);
    acc[1] = __builtin_amdgcn_mfma_f32_16x16x32_bf16(wf.v, cb.b1, acc[1], 0, 0, 0);
    acc[2] = __builtin_amdgcn_mfma_f32_16x16x32_bf16(wf.v, cb.b2, acc[2], 0, 0, 0);
    acc[3] = __builtin_amdgcn_mfma_f32_16x16x32_bf16(wf.v, cb.b3, acc[3], 0, 0, 0);
    accS   = __builtin_amdgcn_mfma_f32_16x16x32_bf16(wf.v, ones,  accS,   0, 0, 0);
  };

  BF B0, B1;
  // prologue: DMA strip 0, drain, then B/f2 for slices (0,0) and (0,1)
  dma(0, 0);
  __syncthreads();
  issueBF(B0, 0, 0);
  issueBF(B1, 0, 1);

  for (int t = 0; t < NSTRIP; ++t) {
    const int cur = t & 1, nxt = cur ^ 1;
    const int* ab = abuf[cur];
    // slice 0: refill B0 with (t,2) BEFORE the DMA burst (older in FIFO)
    { BF cb = B0; issueBF(B0, t, 2); computeSlice(cb, ab, 0); }
    // slice 1: refill B1 with (t,3)
    { BF cb = B1; issueBF(B1, t, 3); computeSlice(cb, ab, 1); }
    // DMA burst for strip t+1 (fire-and-forget; nothing waits on it until barrier)
    if (t + 1 < NSTRIP) dma(t + 1, nxt);
    // slice 2: refill B0 with (t+1,0) (younger than DMA; waited only after barrier)
    { BF cb = B0; if (t + 1 < NSTRIP) issueBF(B0, t + 1, 0); computeSlice(cb, ab, 2); }
    // slice 3: refill B1 with (t+1,1)
    { BF cb = B1; if (t + 1 < NSTRIP) issueBF(B1, t + 1, 1); computeSlice(cb, ab, 3); }
    __syncthreads();  // buffer swap: drains DMA(t+1) (~5k cyc old) at full BW
  }

  // epilogue: overlay reduce buffers on abuf, combine 4 j-subranges per rowhalf
  float* pb = (float*)abuf;            // [8][16][68]
  float* sb = pb + 8 * 16 * 68;        // [8][16]
#pragma unroll
  for (int nf = 0; nf < 4; ++nf)
#pragma unroll
    for (int rg = 0; rg < 4; ++rg)
      pb[(wv * 16 + quad * 4 + rg) * 68 + nf * 16 + tn] = acc[nf][rg];
  if (tn == 0) {
#pragma unroll
    for (int rg = 0; rg < 4; ++rg)
      sb[wv * 16 + quad * 4 + rg] = accS[rg];
  }
  __syncthreads();
  for (int tt = tid; tt < 32 * OD; tt += 512) {
    int rr = tt >> 6, cc = tt & 63;
    int rh2 = rr >> 4, r16 = rr & 15;
    float num = pb[((rh2 * 4 + 0) * 16 + r16) * 68 + cc] +
                pb[((rh2 * 4 + 1) * 16 + r16) * 68 + cc] +
                pb[((rh2 * 4 + 2) * 16 + r16) * 68 + cc] +
                pb[((rh2 * 4 + 3) * 16 + r16) * 68 + cc];
    float den = sb[(rh2 * 4 + 0) * 16 + r16] + sb[(rh2 * 4 + 1) * 16 + r16] +
                sb[(rh2 * 4 + 2) * 16 + r16] + sb[(rh2 * 4 + 3) * 16 + r16];
    out[(long)(i0 + rr) * OD + cc] = num / den;
  }
}

extern "C" void kernel_launch(void* const* d_in, const int* in_sizes, int n_in,
                              void* d_out, int out_size, void* d_ws, size_t ws_size,
                              hipStream_t stream) {
  const float* input = (const float*)d_in[0];
  const int* adj     = (const int*)d_in[1];
  const float* W     = (const float*)d_in[2];
  const float* a     = (const float*)d_in[3];
  float* out = (float*)d_out;

  char* ws = (char*)d_ws;
  __hip_bfloat16* hTt = (__hip_bfloat16*)ws;              // 1 MB (tiled)
  float* f1p = (float*)(ws + (size_t)OD * GN * 2);        // 32 KB
  float* f2p = f1p + GN;                                  // 32 KB

  gat_k1<<<256, 256, 0, stream>>>(input, W, a, hTt, f1p, f2p, out);
  gat_k2<<<256, 512, 0, stream>>>(adj, hTt, f1p, f2p, out);
}